// Round 1
// baseline (291.201 us; speedup 1.0000x reference)
//
#include <hip/hip_runtime.h>
#include <cstdint>

// ---------------------------------------------------------------------------
// AttentionModel: out = softmax((xWq^T+bq)(xWk^T+bk)^T / 32) (xWv^T+bv)
// B=4, S=2048, E=1024, fp32 in/out.  bf16 MFMA pipeline.
// R9: port all three GEMMs from the m97 structure (128^2, 2-barrier drain per
// K-step, ~900 TF ceiling, MfmaUtil 37%) to the 8-wave deep-pipelined schedule
// (m201 class): 512 threads, double-buffered LDS, phase-split MFMA clusters
// with setprio, and COUNTED s_waitcnt vmcnt(N) at tile boundaries so next-next
// tile's global_load_lds stay in flight across barriers (never vmcnt(0) in the
// steady-state loop).  Kept proven pieces: XOR granule swizzle (0 conflicts),
// width-16 global_load_lds with pre-swizzled source, fused epilogues
// (proj writes V transposed; scores does exp + atomic rowsum; PV normalizes),
// m89-verified C/D layout.  Tiles per shape for full-GPU balance at 1 blk/CU:
// proj 128x256 (grid 768), scores 256x256 (grid 256), PV 256x128 (grid 256).
// Race safety: stage(t+2 -> buf[p]) is issued only after the barrier that
// ends tile t's compute (all waves' LDS reads of buf[p] complete before it).
// ---------------------------------------------------------------------------

typedef __attribute__((ext_vector_type(8))) short bf16x8;
typedef __attribute__((ext_vector_type(4))) float f32x4;

__device__ __forceinline__ unsigned short f2bf(float f) {
  union { float f; uint32_t u; } x; x.f = f;
  uint32_t u = x.u;
  return (unsigned short)((u + 0x7fffu + ((u >> 16) & 1u)) >> 16);  // RNE
}

__device__ __forceinline__ void async_copy16(const void* g, void* l) {
  __builtin_amdgcn_global_load_lds(
      (const __attribute__((address_space(1))) void*)g,
      (__attribute__((address_space(3))) void*)l, 16, 0, 0);
}

#define FENCE() asm volatile("" ::: "memory")

__device__ __forceinline__ void wg_bar() {
  FENCE();
  __builtin_amdgcn_s_barrier();
  FENCE();
}

template <int N>
__device__ __forceinline__ void vm_wait() {
  if constexpr (N == 0)      asm volatile("s_waitcnt vmcnt(0)" ::: "memory");
  else if constexpr (N == 6) asm volatile("s_waitcnt vmcnt(6)" ::: "memory");
  else                       asm volatile("s_waitcnt vmcnt(8)" ::: "memory");
}

// ---------------------------------------------------------------------------
// Merged fp32->bf16 convert for x, Wq, Wk, Wv; last block zeroes rowsum.
// ---------------------------------------------------------------------------
__global__ __launch_bounds__(256) void convert_all(
    const float* __restrict__ x, const float* __restrict__ Wq,
    const float* __restrict__ Wk, const float* __restrict__ Wv,
    unsigned short* __restrict__ xb, unsigned short* __restrict__ Wb,
    float* __restrict__ rowsum) {
  const long X4 = (long)8192 * 1024 / 4;
  const long W4 = (long)1024 * 1024 / 4;
  if (blockIdx.x == gridDim.x - 1) {
    float4* r = (float4*)rowsum;
#pragma unroll
    for (int t = 0; t < 8; ++t)
      r[threadIdx.x + t * 256] = float4{0.f, 0.f, 0.f, 0.f};
    return;
  }
  long i = (long)blockIdx.x * 256 + threadIdx.x;
  const float* src; unsigned short* dst; long off;
  if (i < X4)             { src = x;  dst = xb;                    off = i; }
  else if (i < X4 + W4)   { src = Wq; dst = Wb;                    off = i - X4; }
  else if (i < X4 + 2*W4) { src = Wk; dst = Wb + (long)1024*1024;  off = i - X4 - W4; }
  else                    { src = Wv; dst = Wb + (long)2048*1024;  off = i - X4 - 2*W4; }
  const float4 v = ((const float4*)src)[off];
  ushort4 o;
  o.x = f2bf(v.x); o.y = f2bf(v.y); o.z = f2bf(v.z); o.w = f2bf(v.w);
  ((ushort4*)dst)[off] = o;
}

// ---------------------------------------------------------------------------
// C[M,N] = op( scale * (A[M,K] x B[N,K]^T) + bias )
// MODE 0 (PROJ):   bf16 out; z<2 -> normal rows; z==2 -> write V transposed
// MODE 1 (SCORES): bf16 out = exp(scale*acc); atomicAdd per-row sums
// MODE 2 (PV):     fp32 out = acc * (1/rowsum[row])
// 512 threads = 8 waves (WM x WN), BM x BN tile, BK=64, 16x16x32 bf16 MFMA.
// Deep pipeline: dbuf LDS, counted vmcnt at tile boundaries, phase-split
// MFMA with setprio.  Per-wave output (BM/WM) x 64, N_rep==4 always.
// ---------------------------------------------------------------------------
template <int MODE, int BM, int BN, int WM, int WN>
__global__ __launch_bounds__(512, 2) void gemm_bt(
    const unsigned short* __restrict__ Ab, const unsigned short* __restrict__ Bb,
    unsigned short* __restrict__ Cb, float* __restrict__ Cf,
    unsigned short* __restrict__ VT,
    const float* __restrict__ bias0, const float* __restrict__ bias1,
    const float* __restrict__ bias2, float* __restrict__ rowsum,
    int K, int N, float scale, long sA, long sB, long sC) {
  static_assert(WM * WN == 8, "8 waves");
  static_assert(BN / WN == 64, "per-wave col span must be 64");
  constexpr int M_rep = BM / WM / 16;   // 4 or 8
  constexpr int N_rep = 4;
  constexpr int PH    = M_rep / 2;      // phases per K-tile (2 or 4)
  constexpr int LA    = BM / 64;        // A loads / thread / K-tile
  constexpr int LB    = BN / 64;        // B loads / thread / K-tile
  constexpr int LOADS = LA + LB;        // 6 or 8

  __shared__ unsigned short As[2][BM * 64];
  __shared__ unsigned short Bs[2][BN * 64];

  // --- bijective XCD-chunk block remap (all grids are multiples of 8) ---
  const int gx = gridDim.x, gy = gridDim.y;
  const int nwg = gx * gy * (int)gridDim.z;
  int flat = ((int)blockIdx.z * gy + (int)blockIdx.y) * gx + (int)blockIdx.x;
  flat = (flat & 7) * (nwg >> 3) + (flat >> 3);
  const int bx = flat % gx;
  const int r2 = flat / gx;
  const int by = r2 % gy;
  const int z  = r2 / gy;

  const int tile_m = bx * BM;
  const int tile_n = by * BN;

  const unsigned short* A  = Ab + (long)z * sA;
  const unsigned short* Bm = Bb + (long)z * sB;

  const int tid  = threadIdx.x;
  const int lane = tid & 63;
  const int wave = tid >> 6;
  const int l15  = lane & 15;
  const int quad = lane >> 4;
  const int wn   = wave % WN;
  const int wm   = wave / WN;
  const int wmr  = wm * (BM / WM);  // wave row base
  const int wnc  = wn * 64;         // wave col base

  // --- staging map (proven swizzle): each load instr covers 8 rows x 64 k.
  // Lane L -> row +(L>>3), LDS granule L&7; content = chunk (L&7)^(L>>3),
  // so physical granule s of row r holds logical chunk s^(r&7).
  const int rs8 = lane >> 3;
  const int kc  = (lane & 7) ^ rs8;
  const long lK = (long)K;
  const unsigned short* gA0 = A  + (long)(tile_m + wave * (BM / 8) + rs8) * lK + kc * 8;
  const unsigned short* gB0 = Bm + (long)(tile_n + wave * (BN / 8) + rs8) * lK + kc * 8;

  auto stage = [&](int k0, int pb) {
    unsigned short* la = &As[pb][(wave * (BM / 8)) * 64];
    unsigned short* lb = &Bs[pb][(wave * (BN / 8)) * 64];
#pragma unroll
    for (int t = 0; t < LA; ++t)
      async_copy16(gA0 + (long)(t * 8) * lK + k0, la + t * 8 * 64);
#pragma unroll
    for (int t = 0; t < LB; ++t)
      async_copy16(gB0 + (long)(t * 8) * lK + k0, lb + t * 8 * 64);
  };

  const int NT = K >> 6;
  f32x4 acc[M_rep][N_rep] = {};

  // prologue: tiles 0 and 1 in flight; wait only tile 0 (vmcnt == LOADS)
  stage(0, 0);
  stage(64, 1);
  vm_wait<LOADS>();
  wg_bar();

  int p = 0;
  for (int t = 0; t < NT; ++t) {
    const unsigned short* as = &As[p][0];
    const unsigned short* bs = &Bs[p][0];
    bf16x8 bfr[N_rep][2];
#pragma unroll
    for (int ph = 0; ph < PH; ++ph) {
      // fragment granule: physical = (kk*4+quad) ^ (row&7), row&7 == l15&7
      bf16x8 af[2][2];
#pragma unroll
      for (int ii = 0; ii < 2; ++ii) {
        const int row = wmr + (ph * 2 + ii) * 16 + l15;
#pragma unroll
        for (int kk = 0; kk < 2; ++kk)
          af[ii][kk] = *(const bf16x8*)&as[row * 64 + (((kk * 4 + quad) ^ (l15 & 7)) << 3)];
      }
      if (ph == 0) {  // B frags resident for the whole K-tile
#pragma unroll
        for (int j = 0; j < N_rep; ++j) {
          const int row = wnc + j * 16 + l15;
#pragma unroll
          for (int kk = 0; kk < 2; ++kk)
            bfr[j][kk] = *(const bf16x8*)&bs[row * 64 + (((kk * 4 + quad) ^ (l15 & 7)) << 3)];
        }
      }
      wg_bar();                       // lockstep: all waves enter MFMA cluster
      __builtin_amdgcn_s_setprio(1);
#pragma unroll
      for (int ii = 0; ii < 2; ++ii)
#pragma unroll
        for (int j = 0; j < N_rep; ++j)
#pragma unroll
          for (int kk = 0; kk < 2; ++kk)
            acc[ph * 2 + ii][j] = __builtin_amdgcn_mfma_f32_16x16x32_bf16(
                af[ii][kk], bfr[j][kk], acc[ph * 2 + ii][j], 0, 0, 0);
      __builtin_amdgcn_s_setprio(0);
      wg_bar();
    }
    // --- tile boundary: buf[p] is now dead (all waves past last barrier) ---
    if (t + 2 < NT) {
      stage((t + 2) << 6, p);   // issue next-next tile into freed buffer
      vm_wait<LOADS>();         // wait tile t+1 landed; t+2 stays in flight
      wg_bar();
    } else if (t + 1 < NT) {
      vm_wait<0>();             // epilogue of pipeline: drain last tile
      wg_bar();
    }
    p ^= 1;
  }

  // ------------------------- epilogue -------------------------
  // C/D layout: col = lane&15, row = quad*4 + reg (m89-verified)
  if constexpr (MODE == 0) {
    const float* bias = (z == 0) ? bias0 : (z == 1) ? bias1 : bias2;
    if (z == 2) {
      // write V transposed: VT[b][f][s], b = row>>11, s = row&2047
#pragma unroll
      for (int j = 0; j < N_rep; ++j) {
        const int col = tile_n + wnc + j * 16 + l15;  // feature f
        const float bv = bias[col];
#pragma unroll
        for (int i = 0; i < M_rep; ++i) {
          const int row0 = tile_m + wmr + i * 16 + quad * 4;  // token
          const int b = row0 >> 11;
          const int sx = row0 & 2047;
          ushort4 o;
          o.x = f2bf(acc[i][j][0] + bv);
          o.y = f2bf(acc[i][j][1] + bv);
          o.z = f2bf(acc[i][j][2] + bv);
          o.w = f2bf(acc[i][j][3] + bv);
          *(ushort4*)&VT[(long)b * 1024 * 2048 + (long)col * 2048 + sx] = o;
        }
      }
    } else {
      unsigned short* Cbz = Cb + (long)z * sC;
#pragma unroll
      for (int j = 0; j < N_rep; ++j) {
        const int col = tile_n + wnc + j * 16 + l15;
        const float bv = bias[col];
#pragma unroll
        for (int i = 0; i < M_rep; ++i) {
          const int row0 = tile_m + wmr + i * 16 + quad * 4;
#pragma unroll
          for (int r = 0; r < 4; ++r)
            Cbz[(long)(row0 + r) * N + col] = f2bf(acc[i][j][r] + bv);
        }
      }
    }
  } else if constexpr (MODE == 1) {
    // exp epilogue + row-sum atomics
    unsigned short* Cbz = Cb + (long)z * sC;
    float part[M_rep * 4];
#pragma unroll
    for (int t = 0; t < M_rep * 4; ++t) part[t] = 0.0f;
#pragma unroll
    for (int j = 0; j < N_rep; ++j) {
      const int col = tile_n + wnc + j * 16 + l15;
#pragma unroll
      for (int i = 0; i < M_rep; ++i) {
        const int row0 = tile_m + wmr + i * 16 + quad * 4;
#pragma unroll
        for (int r = 0; r < 4; ++r) {
          const float e = __expf(acc[i][j][r] * scale);
          part[i * 4 + r] += e;
          Cbz[(long)(row0 + r) * N + col] = f2bf(e);
        }
      }
    }
    // reduce across the 16 lanes (l15) sharing each row
#pragma unroll
    for (int t = 0; t < M_rep * 4; ++t)
#pragma unroll
      for (int o = 1; o < 16; o <<= 1)
        part[t] += __shfl_xor(part[t], o);
    if (l15 == 0) {
#pragma unroll
      for (int i = 0; i < M_rep; ++i) {
        const int row0 = tile_m + wmr + i * 16 + quad * 4;
#pragma unroll
        for (int r = 0; r < 4; ++r)
          atomicAdd(&rowsum[z * 2048 + row0 + r], part[i * 4 + r]);
      }
    }
  } else {
    // PV: normalize by rowsum
    float* Cfz = Cf + (long)z * sC;
    float inv[M_rep * 4];
#pragma unroll
    for (int i = 0; i < M_rep; ++i) {
      const int row0 = tile_m + wmr + i * 16 + quad * 4;
#pragma unroll
      for (int r = 0; r < 4; ++r)
        inv[i * 4 + r] = 1.0f / rowsum[z * 2048 + row0 + r];
    }
#pragma unroll
    for (int j = 0; j < N_rep; ++j) {
      const int col = tile_n + wnc + j * 16 + l15;
#pragma unroll
      for (int i = 0; i < M_rep; ++i) {
        const int row0 = tile_m + wmr + i * 16 + quad * 4;
#pragma unroll
        for (int r = 0; r < 4; ++r)
          Cfz[(long)(row0 + r) * N + col] = acc[i][j][r] * inv[i * 4 + r];
      }
    }
  }
}

// ---------------------------------------------------------------------------
extern "C" void kernel_launch(void* const* d_in, const int* in_sizes, int n_in,
                              void* d_out, int out_size, void* d_ws, size_t ws_size,
                              hipStream_t stream) {
  const float* x  = (const float*)d_in[0];
  const float* Wq = (const float*)d_in[1];
  const float* bq = (const float*)d_in[2];
  const float* Wk = (const float*)d_in[3];
  const float* bk = (const float*)d_in[4];
  const float* Wv = (const float*)d_in[5];
  const float* bv = (const float*)d_in[6];
  float* out = (float*)d_out;

  constexpr int Bt = 4, S = 2048, E = 1024;
  constexpr int M = Bt * S;  // 8192

  // ws layout (bf16): x_bf | W_bf(3) | Q | K | VT | P(exp scores) | rowsum(f32)
  unsigned short* xb = (unsigned short*)d_ws;
  unsigned short* Wb = xb + (size_t)M * E;
  unsigned short* Q  = Wb + (size_t)3 * E * E;
  unsigned short* Kb = Q + (size_t)M * E;
  unsigned short* VT = Kb + (size_t)M * E;
  unsigned short* P  = VT + (size_t)M * E;
  float* rowsum = (float*)(P + (size_t)Bt * S * S);

  // 1) converts + rowsum zeroing (one launch)
  const int conv_blocks = (M * E / 4 + 3 * (E * E / 4)) / 256 + 1;
  convert_all<<<dim3(conv_blocks), dim3(256), 0, stream>>>(x, Wq, Wk, Wv, xb, Wb, rowsum);

  // 2) projections: z in {Q,K,V}; y = x W^T + b; V written transposed
  //    128x256 tile -> grid 64x4x3 = 768 blocks (3 balanced rounds on 256 CUs)
  gemm_bt<0, 128, 256, 2, 4><<<dim3(M / 128, E / 256, 3), dim3(512), 0, stream>>>(
      xb, Wb, Q, nullptr, VT, bq, bk, bv, nullptr, E, E, 1.0f,
      0L, (long)E * E, (long)M * E);

  // 3) P = exp(Q K^T / 32) (unnormalized) + row sums
  //    256x256 tile -> grid 8x8x4 = 256 blocks (1 per CU)
  gemm_bt<1, 256, 256, 2, 4><<<dim3(S / 256, S / 256, Bt), dim3(512), 0, stream>>>(
      Q, Kb, P, nullptr, nullptr, nullptr, nullptr, nullptr, rowsum,
      E, S, 1.0f / 32.0f, (long)S * E, (long)S * E, (long)S * S);

  // 4) out = (P V) / rowsum   (fp32 out)
  //    256x128 tile -> grid 8x8x4 = 256 blocks (1 per CU)
  gemm_bt<2, 256, 128, 4, 2><<<dim3(S / 256, E / 128, Bt), dim3(512), 0, stream>>>(
      P, VT, nullptr, out, nullptr, nullptr, nullptr, nullptr, rowsum,
      S, E, 1.0f, (long)S * S, (long)E * S, (long)S * E);
}

// Round 2
// 288.728 us; speedup vs baseline: 1.0086x; 1.0086x over previous
//
#include <hip/hip_runtime.h>
#include <cstdint>

// ---------------------------------------------------------------------------
// AttentionModel: out = softmax((xWq^T+bq)(xWk^T+bk)^T / 32) (xWv^T+bv)
// B=4, S=2048, E=1024, fp32 in/out.  bf16 MFMA pipeline.
// R10: fix R9's two defects.
//  (1) Prefetch depth: R9's 2-buffer dbuf gave only 1 K-tile of latency cover
//      (~600cyc < 900cyc HBM) -> every boundary stalled, MfmaUtil 20%.
//      Now 3-buffer rotation: stage(t+3) issued at end of tile t, boundary
//      vm_wait<12> waits only for tile t+1 (issued 2 full tiles ago).
//      Uniform 256x128 tile so 3 bufs fit LDS: (256+128)*64*2*3 = 144 KiB.
//  (2) L2 locality: R9's XCD-chunk remap streamed whole matrices through one
//      L2 (FETCH 104 MB vs 43).  Restore R8's proven 8x8 super-tile swizzle
//      (64 consecutive blocks = 8x8 tile patch, co-resident across XCDs).
// Kept: 8 waves, double-barrier phases + setprio (m201 schedule), counted
// vmcnt never 0 in steady loop, XOR granule swizzle (0 conflicts), width-16
// global_load_lds, fused epilogues, m89-verified C/D layout.
// ---------------------------------------------------------------------------

typedef __attribute__((ext_vector_type(8))) short bf16x8;
typedef __attribute__((ext_vector_type(4))) float f32x4;

__device__ __forceinline__ unsigned short f2bf(float f) {
  union { float f; uint32_t u; } x; x.f = f;
  uint32_t u = x.u;
  return (unsigned short)((u + 0x7fffu + ((u >> 16) & 1u)) >> 16);  // RNE
}

__device__ __forceinline__ void async_copy16(const void* g, void* l) {
  __builtin_amdgcn_global_load_lds(
      (const __attribute__((address_space(1))) void*)g,
      (__attribute__((address_space(3))) void*)l, 16, 0, 0);
}

#define FENCE() asm volatile("" ::: "memory")

__device__ __forceinline__ void wg_bar() {
  FENCE();
  __builtin_amdgcn_s_barrier();
  FENCE();
}

template <int N>
__device__ __forceinline__ void vm_wait() {
  if constexpr (N == 0)       asm volatile("s_waitcnt vmcnt(0)" ::: "memory");
  else if constexpr (N == 6)  asm volatile("s_waitcnt vmcnt(6)" ::: "memory");
  else if constexpr (N == 12) asm volatile("s_waitcnt vmcnt(12)" ::: "memory");
  else                        asm volatile("s_waitcnt vmcnt(8)" ::: "memory");
}

// ---------------------------------------------------------------------------
// Merged fp32->bf16 convert for x, Wq, Wk, Wv; last block zeroes rowsum.
// ---------------------------------------------------------------------------
__global__ __launch_bounds__(256) void convert_all(
    const float* __restrict__ x, const float* __restrict__ Wq,
    const float* __restrict__ Wk, const float* __restrict__ Wv,
    unsigned short* __restrict__ xb, unsigned short* __restrict__ Wb,
    float* __restrict__ rowsum) {
  const long X4 = (long)8192 * 1024 / 4;
  const long W4 = (long)1024 * 1024 / 4;
  if (blockIdx.x == gridDim.x - 1) {
    float4* r = (float4*)rowsum;
#pragma unroll
    for (int t = 0; t < 8; ++t)
      r[threadIdx.x + t * 256] = float4{0.f, 0.f, 0.f, 0.f};
    return;
  }
  long i = (long)blockIdx.x * 256 + threadIdx.x;
  const float* src; unsigned short* dst; long off;
  if (i < X4)             { src = x;  dst = xb;                    off = i; }
  else if (i < X4 + W4)   { src = Wq; dst = Wb;                    off = i - X4; }
  else if (i < X4 + 2*W4) { src = Wk; dst = Wb + (long)1024*1024;  off = i - X4 - W4; }
  else                    { src = Wv; dst = Wb + (long)2048*1024;  off = i - X4 - 2*W4; }
  const float4 v = ((const float4*)src)[off];
  ushort4 o;
  o.x = f2bf(v.x); o.y = f2bf(v.y); o.z = f2bf(v.z); o.w = f2bf(v.w);
  ((ushort4*)dst)[off] = o;
}

// ---------------------------------------------------------------------------
// C[M,N] = op( scale * (A[M,K] x B[N,K]^T) + bias )
// MODE 0 (PROJ):   bf16 out; z<2 -> normal rows; z==2 -> write V transposed
// MODE 1 (SCORES): bf16 out = exp(scale*acc); atomicAdd per-row sums
// MODE 2 (PV):     fp32 out = acc * (1/rowsum[row])
// 512 threads = 8 waves (WMxWN=4x2), 256x128 tile, BK=64, 16x16x32 bf16 MFMA.
// 3-buffer LDS rotation, counted vmcnt (12/6/0), 2 phases x 16 MFMA with
// setprio, double barriers per phase.  8x8 super-tile block swizzle.
// ---------------------------------------------------------------------------
template <int MODE, int BM, int BN, int WM, int WN>
__global__ __launch_bounds__(512, 2) void gemm_bt(
    const unsigned short* __restrict__ Ab, const unsigned short* __restrict__ Bb,
    unsigned short* __restrict__ Cb, float* __restrict__ Cf,
    unsigned short* __restrict__ VT,
    const float* __restrict__ bias0, const float* __restrict__ bias1,
    const float* __restrict__ bias2, float* __restrict__ rowsum,
    int K, int N, float scale, long sA, long sB, long sC) {
  static_assert(WM * WN == 8, "8 waves");
  static_assert(BM / WM == 64, "per-wave row span 64");
  static_assert(BN / WN == 64, "per-wave col span 64");
  constexpr int M_rep = 4;
  constexpr int N_rep = 4;
  constexpr int LA    = BM / 64;        // A loads / thread / K-tile (4)
  constexpr int LB    = BN / 64;        // B loads / thread / K-tile (2)
  constexpr int LOADS = LA + LB;        // 6

  __shared__ unsigned short As[3][BM * 64];
  __shared__ unsigned short Bs[3][BN * 64];

  const int z = blockIdx.z;
  const unsigned short* A  = Ab + (long)z * sA;
  const unsigned short* Bm = Bb + (long)z * sB;

  const int tid  = threadIdx.x;
  const int lane = tid & 63;
  const int wave = tid >> 6;
  const int l15  = lane & 15;
  const int quad = lane >> 4;
  const int wn   = wave % WN;
  const int wm   = wave / WN;
  const int wmr  = wm * 64;   // wave row base
  const int wnc  = wn * 64;   // wave col base

  // --- 8x8 super-tile swizzle for L2 locality (R8-proven) ---
  const int bxd  = gridDim.x;
  const int flat = blockIdx.y * bxd + blockIdx.x;
  const int st = flat >> 6;          // super-tile index (64 blocks each)
  const int inside = flat & 63;
  const int nstx = bxd >> 3;
  const int stx = st % nstx;
  const int sty = st / nstx;
  const int tile_m = (stx * 8 + (inside & 7)) * BM;
  const int tile_n = (sty * 8 + (inside >> 3)) * BN;

  // --- staging map: wave w covers A rows [w*BM/8, +BM/8), B rows [w*BN/8,..).
  // Lane L -> row +(L>>3), LDS granule L&7; content = chunk (L&7)^(L>>3),
  // so physical granule s of row r holds logical chunk s^(r&7).
  const int rs8 = lane >> 3;
  const int kc  = (lane & 7) ^ rs8;
  const long lK = (long)K;
  const unsigned short* gA0 = A  + (long)(tile_m + wave * (BM / 8) + rs8) * lK + kc * 8;
  const unsigned short* gB0 = Bm + (long)(tile_n + wave * (BN / 8) + rs8) * lK + kc * 8;

  auto stage = [&](int k0, int pb) {
    unsigned short* la = &As[pb][(wave * (BM / 8)) * 64];
    unsigned short* lb = &Bs[pb][(wave * (BN / 8)) * 64];
#pragma unroll
    for (int t = 0; t < LA; ++t)
      async_copy16(gA0 + (long)(t * 8) * lK + k0, la + t * 8 * 64);
#pragma unroll
    for (int t = 0; t < LB; ++t)
      async_copy16(gB0 + (long)(t * 8) * lK + k0, lb + t * 8 * 64);
  };

  const int NT = K >> 6;
  f32x4 acc[M_rep][N_rep] = {};

  // prologue: tiles 0,1,2 in flight; wait only tile 0 (12 = 2*LOADS remain)
  stage(0, 0);
  stage(64, 1);
  stage(128, 2);
  vm_wait<2 * LOADS>();
  wg_bar();

  int cur = 0;
  for (int t = 0; t < NT; ++t) {
    const unsigned short* as = &As[cur][0];
    const unsigned short* bs = &Bs[cur][0];
    bf16x8 bfr[N_rep][2];
#pragma unroll
    for (int ph = 0; ph < 2; ++ph) {
      // fragment granule: physical = (kk*4+quad) ^ (row&7), row&7 == l15&7
      bf16x8 af[2][2];
#pragma unroll
      for (int ii = 0; ii < 2; ++ii) {
        const int row = wmr + (ph * 2 + ii) * 16 + l15;
#pragma unroll
        for (int kk = 0; kk < 2; ++kk)
          af[ii][kk] = *(const bf16x8*)&as[row * 64 + (((kk * 4 + quad) ^ (l15 & 7)) << 3)];
      }
      if (ph == 0) {  // B frags resident for the whole K-tile
#pragma unroll
        for (int j = 0; j < N_rep; ++j) {
          const int row = wnc + j * 16 + l15;
#pragma unroll
          for (int kk = 0; kk < 2; ++kk)
            bfr[j][kk] = *(const bf16x8*)&bs[row * 64 + (((kk * 4 + quad) ^ (l15 & 7)) << 3)];
        }
      }
      wg_bar();                       // all waves enter MFMA cluster together
      __builtin_amdgcn_s_setprio(1);
#pragma unroll
      for (int ii = 0; ii < 2; ++ii)
#pragma unroll
        for (int j = 0; j < N_rep; ++j)
#pragma unroll
          for (int kk = 0; kk < 2; ++kk)
            acc[ph * 2 + ii][j] = __builtin_amdgcn_mfma_f32_16x16x32_bf16(
                af[ii][kk], bfr[j][kk], acc[ph * 2 + ii][j], 0, 0, 0);
      __builtin_amdgcn_s_setprio(0);
      wg_bar();
    }
    // --- tile boundary: buf[cur] dead (all waves past last phase barrier) ---
    if (t + 3 < NT) {
      stage((t + 3) << 6, cur);   // issue tile t+3 into freed buffer
      vm_wait<2 * LOADS>();       // wait tile t+1 landed; t+2,t+3 in flight
      wg_bar();
    } else if (t + 3 == NT) {
      vm_wait<LOADS>();           // tiles t+1,t+2 in flight; wait t+1
      wg_bar();
    } else if (t + 2 == NT) {
      vm_wait<0>();               // drain final tile
      wg_bar();
    }
    cur = (cur == 2) ? 0 : cur + 1;
  }

  // ------------------------- epilogue -------------------------
  // C/D layout: col = lane&15, row = quad*4 + reg (m89-verified)
  if constexpr (MODE == 0) {
    const float* bias = (z == 0) ? bias0 : (z == 1) ? bias1 : bias2;
    if (z == 2) {
      // write V transposed: VT[b][f][s], b = row>>11, s = row&2047
#pragma unroll
      for (int j = 0; j < N_rep; ++j) {
        const int col = tile_n + wnc + j * 16 + l15;  // feature f
        const float bv = bias[col];
#pragma unroll
        for (int i = 0; i < M_rep; ++i) {
          const int row0 = tile_m + wmr + i * 16 + quad * 4;  // token
          const int b = row0 >> 11;
          const int sx = row0 & 2047;
          ushort4 o;
          o.x = f2bf(acc[i][j][0] + bv);
          o.y = f2bf(acc[i][j][1] + bv);
          o.z = f2bf(acc[i][j][2] + bv);
          o.w = f2bf(acc[i][j][3] + bv);
          *(ushort4*)&VT[(long)b * 1024 * 2048 + (long)col * 2048 + sx] = o;
        }
      }
    } else {
      unsigned short* Cbz = Cb + (long)z * sC;
#pragma unroll
      for (int j = 0; j < N_rep; ++j) {
        const int col = tile_n + wnc + j * 16 + l15;
        const float bv = bias[col];
#pragma unroll
        for (int i = 0; i < M_rep; ++i) {
          const int row0 = tile_m + wmr + i * 16 + quad * 4;
#pragma unroll
          for (int r = 0; r < 4; ++r)
            Cbz[(long)(row0 + r) * N + col] = f2bf(acc[i][j][r] + bv);
        }
      }
    }
  } else if constexpr (MODE == 1) {
    // exp epilogue + row-sum atomics
    unsigned short* Cbz = Cb + (long)z * sC;
    float part[M_rep * 4];
#pragma unroll
    for (int t = 0; t < M_rep * 4; ++t) part[t] = 0.0f;
#pragma unroll
    for (int j = 0; j < N_rep; ++j) {
      const int col = tile_n + wnc + j * 16 + l15;
#pragma unroll
      for (int i = 0; i < M_rep; ++i) {
        const int row0 = tile_m + wmr + i * 16 + quad * 4;
#pragma unroll
        for (int r = 0; r < 4; ++r) {
          const float e = __expf(acc[i][j][r] * scale);
          part[i * 4 + r] += e;
          Cbz[(long)(row0 + r) * N + col] = f2bf(e);
        }
      }
    }
    // reduce across the 16 lanes (l15) sharing each row
#pragma unroll
    for (int t = 0; t < M_rep * 4; ++t)
#pragma unroll
      for (int o = 1; o < 16; o <<= 1)
        part[t] += __shfl_xor(part[t], o);
    if (l15 == 0) {
#pragma unroll
      for (int i = 0; i < M_rep; ++i) {
        const int row0 = tile_m + wmr + i * 16 + quad * 4;
#pragma unroll
        for (int r = 0; r < 4; ++r)
          atomicAdd(&rowsum[z * 2048 + row0 + r], part[i * 4 + r]);
      }
    }
  } else {
    // PV: normalize by rowsum
    float* Cfz = Cf + (long)z * sC;
    float inv[M_rep * 4];
#pragma unroll
    for (int i = 0; i < M_rep; ++i) {
      const int row0 = tile_m + wmr + i * 16 + quad * 4;
#pragma unroll
      for (int r = 0; r < 4; ++r)
        inv[i * 4 + r] = 1.0f / rowsum[z * 2048 + row0 + r];
    }
#pragma unroll
    for (int j = 0; j < N_rep; ++j) {
      const int col = tile_n + wnc + j * 16 + l15;
#pragma unroll
      for (int i = 0; i < M_rep; ++i) {
        const int row0 = tile_m + wmr + i * 16 + quad * 4;
#pragma unroll
        for (int r = 0; r < 4; ++r)
          Cfz[(long)(row0 + r) * N + col] = acc[i][j][r] * inv[i * 4 + r];
      }
    }
  }
}

// ---------------------------------------------------------------------------
extern "C" void kernel_launch(void* const* d_in, const int* in_sizes, int n_in,
                              void* d_out, int out_size, void* d_ws, size_t ws_size,
                              hipStream_t stream) {
  const float* x  = (const float*)d_in[0];
  const float* Wq = (const float*)d_in[1];
  const float* bq = (const float*)d_in[2];
  const float* Wk = (const float*)d_in[3];
  const float* bk = (const float*)d_in[4];
  const float* Wv = (const float*)d_in[5];
  const float* bv = (const float*)d_in[6];
  float* out = (float*)d_out;

  constexpr int Bt = 4, S = 2048, E = 1024;
  constexpr int M = Bt * S;  // 8192

  // ws layout (bf16): x_bf | W_bf(3) | Q | K | VT | P(exp scores) | rowsum(f32)
  unsigned short* xb = (unsigned short*)d_ws;
  unsigned short* Wb = xb + (size_t)M * E;
  unsigned short* Q  = Wb + (size_t)3 * E * E;
  unsigned short* Kb = Q + (size_t)M * E;
  unsigned short* VT = Kb + (size_t)M * E;
  unsigned short* P  = VT + (size_t)M * E;
  float* rowsum = (float*)(P + (size_t)Bt * S * S);

  // 1) converts + rowsum zeroing (one launch)
  const int conv_blocks = (M * E / 4 + 3 * (E * E / 4)) / 256 + 1;
  convert_all<<<dim3(conv_blocks), dim3(256), 0, stream>>>(x, Wq, Wk, Wv, xb, Wb, rowsum);

  // 2) projections: z in {Q,K,V}; y = x W^T + b; V written transposed
  //    256x128 tile -> grid 32x8x3 = 768 blocks
  gemm_bt<0, 256, 128, 4, 2><<<dim3(M / 256, E / 128, 3), dim3(512), 0, stream>>>(
      xb, Wb, Q, nullptr, VT, bq, bk, bv, nullptr, E, E, 1.0f,
      0L, (long)E * E, (long)M * E);

  // 3) P = exp(Q K^T / 32) (unnormalized) + row sums
  //    256x128 tile -> grid 8x16x4 = 512 blocks
  gemm_bt<1, 256, 128, 4, 2><<<dim3(S / 256, S / 128, Bt), dim3(512), 0, stream>>>(
      Q, Kb, P, nullptr, nullptr, nullptr, nullptr, nullptr, rowsum,
      E, S, 1.0f / 32.0f, (long)S * E, (long)S * E, (long)S * S);

  // 4) out = (P V) / rowsum   (fp32 out)
  //    256x128 tile -> grid 8x8x4 = 256 blocks
  gemm_bt<2, 256, 128, 4, 2><<<dim3(S / 256, E / 128, Bt), dim3(512), 0, stream>>>(
      P, VT, nullptr, out, nullptr, nullptr, nullptr, nullptr, rowsum,
      S, E, 1.0f, (long)S * S, (long)E * S, (long)S * E);
}